// Round 7
// baseline (316.490 us; speedup 1.0000x reference)
//
#include <hip/hip_runtime.h>

#define NN 50000
#define NE 800000
#define IND 768
#define CH  128   // output channels per node for both layers
#define NBLK 196  // ceil(NN/256)

typedef __attribute__((ext_vector_type(8))) short bf16x8;
typedef __attribute__((ext_vector_type(4))) float f32x4;

// ---------------- bf16 split helpers ----------------
__device__ __forceinline__ unsigned short bf16_rne(float f) {
    unsigned u = __float_as_uint(f);
    u += 0x7fffu + ((u >> 16) & 1u);
    return (unsigned short)(u >> 16);
}
__device__ __forceinline__ float bf16_to_f(unsigned short b) {
    return __uint_as_float(((unsigned)b) << 16);
}

// ---------------- prep: W -> K-tiled, 8-way-swizzled bf16 hi/lo planes ----------------
// Per plane: [K/32 tiles][4096 ushorts]. Within a tile, row n (0..127) has 4 granules
// (16B = 8 bf16). Logical granule j of row n stored at g = n*4 + (j ^ ((n>>1)&3)).
// GEMM stages each 8KB tile linearly via global_load_lds and reads granule
// n*4 + (kg ^ ((n>>1)&3)) -> 16 same-kg lanes spread over 8 bank-quads (2/quad, free).
__global__ void prep_b1(const float* __restrict__ W1,
                        unsigned short* __restrict__ Bhi, unsigned short* __restrict__ Blo)
{
    int idx = blockIdx.x * blockDim.x + threadIdx.x;   // n*IND + k
    if (idx >= CH * IND) return;
    int n = idx / IND, k = idx % IND;
    float v = W1[(size_t)(n >> 5) * IND * 32 + (size_t)k * 32 + (n & 31)];
    int kt = k >> 5, kk = k & 31, j = kk >> 3, e = kk & 7;
    int g = n * 4 + (j ^ ((n >> 1) & 3));
    int off = kt * 4096 + g * 8 + e;
    unsigned short hi = bf16_rne(v);
    float lo = v - bf16_to_f(hi);
    Bhi[off] = hi;
    Blo[off] = bf16_rne(lo);
}

__global__ void prep_b2(const float* __restrict__ W2,
                        unsigned short* __restrict__ Bhi, unsigned short* __restrict__ Blo)
{
    int idx = blockIdx.x * blockDim.x + threadIdx.x;   // n*CH + k
    if (idx >= CH * CH) return;
    int n = idx / CH, k = idx % CH;
    float v = W2[(size_t)k * CH + n];
    int kt = k >> 5, kk = k & 31, j = kk >> 3, e = kk & 7;
    int g = n * 4 + (j ^ ((n >> 1) & 3));
    int off = kt * 4096 + g * 8 + e;
    unsigned short hi = bf16_rne(v);
    float lo = v - bf16_to_f(hi);
    Bhi[off] = hi;
    Blo[off] = bf16_rne(lo);
}

// ---------------- GEMM: C[M x 128] = A[M x K] * B[K x 128], split-bf16 MFMA ----------------
// GBM=64, 2-phase double-buffered pipeline: issue next-tile A loads (regs) + B DMA,
// compute current tile, convert+write A late, one barrier per tile.
#define GBM 64
#define GBK 32

__global__ __launch_bounds__(256) void gemm_split(
    const float* __restrict__ A,
    const unsigned short* __restrict__ Bthi, const unsigned short* __restrict__ Btlo,
    float* __restrict__ C, int M, int K)
{
    __shared__ unsigned short Ahi[2][2048];    // [buf][64 rows x 4 granules x 8]
    __shared__ unsigned short Alo[2][2048];
    __shared__ unsigned short Bs[2][2][4096];  // [buf][plane][128 rows x 4 granules x 8]

    const int t = threadIdx.x;
    const int lane = t & 63;
    const int w = t >> 6;
    const int wr = w >> 1, wc = w & 1;
    const int lrow = lane & 15, kg = lane >> 4;
    const int m0 = blockIdx.x * GBM;

    // A staging: thread t -> row ar=t>>2, logical granule aj=t&3 (8 fp32)
    const int ar = t >> 2, aj = t & 3;
    const bool avalid = (m0 + ar) < M;
    const float* aptr = A + (size_t)(m0 + ar) * K + aj * 8;
    const int ag8 = (ar * 4 + (aj ^ ((ar >> 1) & 3))) * 8;   // swizzled ushort offset

    // fragment read offsets (ushort index)
    int aoff[2];
    #pragma unroll
    for (int mi = 0; mi < 2; ++mi) {
        const int r = wr * 32 + mi * 16 + lrow;
        aoff[mi] = (r * 4 + (kg ^ ((r >> 1) & 3))) * 8;
    }
    int boff[4];
    #pragma unroll
    for (int ni = 0; ni < 4; ++ni) {
        const int n = wc * 64 + ni * 16 + lrow;
        boff[ni] = (n * 4 + (kg ^ ((n >> 1) & 3))) * 8;
    }

    f32x4 acc[2][4];
    #pragma unroll
    for (int i = 0; i < 2; ++i)
        #pragma unroll
        for (int j = 0; j < 4; ++j) acc[i][j] = (f32x4)(0.f);

    const int nt = K / GBK;

    float4 v0 = make_float4(0.f, 0.f, 0.f, 0.f);
    float4 v1 = make_float4(0.f, 0.f, 0.f, 0.f);

    // ---- prologue: stage tile 0 into buf 0 ----
    if (avalid) { v0 = *(const float4*)aptr; v1 = *(const float4*)(aptr + 4); }
    #pragma unroll
    for (int i = 0; i < 4; ++i) {
        const int c = w * 4 + i;
        const int plane = c >> 3;
        const int co = (c & 7) * 512;
        const unsigned short* gs = (plane ? Btlo : Bthi) + co + lane * 8;
        __builtin_amdgcn_global_load_lds(
            (const __attribute__((address_space(1))) unsigned int*)gs,
            (__attribute__((address_space(3))) unsigned int*)&Bs[0][plane][co],
            16, 0, 0);
    }
    {
        float f[8] = {v0.x, v0.y, v0.z, v0.w, v1.x, v1.y, v1.z, v1.w};
        unsigned short hi[8], lo[8];
        #pragma unroll
        for (int q = 0; q < 8; ++q) {
            hi[q] = bf16_rne(f[q]);
            lo[q] = bf16_rne(f[q] - bf16_to_f(hi[q]));
        }
        *(uint4*)&Ahi[0][ag8] = *(uint4*)hi;
        *(uint4*)&Alo[0][ag8] = *(uint4*)lo;
    }
    __syncthreads();

    for (int kt = 0; kt < nt; ++kt) {
        const int buf = kt & 1;
        // ---- issue next tile's loads (A -> regs, B -> DMA into buf^1) ----
        if (kt + 1 < nt) {
            if (avalid) {
                const float* p = aptr + (kt + 1) * GBK;
                v0 = *(const float4*)p;
                v1 = *(const float4*)(p + 4);
            }
            #pragma unroll
            for (int i = 0; i < 4; ++i) {
                const int c = w * 4 + i;
                const int plane = c >> 3;
                const int co = (c & 7) * 512;
                const unsigned short* gs =
                    (plane ? Btlo : Bthi) + (size_t)(kt + 1) * 4096 + co + lane * 8;
                __builtin_amdgcn_global_load_lds(
                    (const __attribute__((address_space(1))) unsigned int*)gs,
                    (__attribute__((address_space(3))) unsigned int*)&Bs[buf ^ 1][plane][co],
                    16, 0, 0);
            }
        }
        // ---- compute current tile ----
        bf16x8 ahi[2], alo[2];
        #pragma unroll
        for (int mi = 0; mi < 2; ++mi) {
            ahi[mi] = *(const bf16x8*)&Ahi[buf][aoff[mi]];
            alo[mi] = *(const bf16x8*)&Alo[buf][aoff[mi]];
        }
        #pragma unroll
        for (int ni = 0; ni < 4; ++ni) {
            const bf16x8 bhi = *(const bf16x8*)&Bs[buf][0][boff[ni]];
            const bf16x8 blo = *(const bf16x8*)&Bs[buf][1][boff[ni]];
            #pragma unroll
            for (int mi = 0; mi < 2; ++mi) {
                acc[mi][ni] = __builtin_amdgcn_mfma_f32_16x16x32_bf16(ahi[mi], bhi, acc[mi][ni], 0, 0, 0);
                acc[mi][ni] = __builtin_amdgcn_mfma_f32_16x16x32_bf16(ahi[mi], blo, acc[mi][ni], 0, 0, 0);
                acc[mi][ni] = __builtin_amdgcn_mfma_f32_16x16x32_bf16(alo[mi], bhi, acc[mi][ni], 0, 0, 0);
            }
        }
        // ---- write next tile's A (late: loads have had the compute phase to land) ----
        if (kt + 1 < nt) {
            float f[8] = {v0.x, v0.y, v0.z, v0.w, v1.x, v1.y, v1.z, v1.w};
            unsigned short hi[8], lo[8];
            #pragma unroll
            for (int q = 0; q < 8; ++q) {
                hi[q] = bf16_rne(f[q]);
                lo[q] = bf16_rne(f[q] - bf16_to_f(hi[q]));
            }
            *(uint4*)&Ahi[buf ^ 1][ag8] = *(uint4*)hi;
            *(uint4*)&Alo[buf ^ 1][ag8] = *(uint4*)lo;
        }
        __syncthreads();   // drains B DMA (vmcnt) + A writes (lgkm); next tile ready
    }

    // ---- C write: col = lane&15, row = (lane>>4)*4 + reg ----
    #pragma unroll
    for (int mi = 0; mi < 2; ++mi) {
        const int rbase = m0 + wr * 32 + mi * 16 + kg * 4;
        #pragma unroll
        for (int ni = 0; ni < 4; ++ni) {
            const int col = wc * 64 + ni * 16 + lrow;
            const f32x4 a = acc[mi][ni];
            #pragma unroll
            for (int j = 0; j < 4; ++j) {
                const int r = rbase + j;
                if (r < M) C[(size_t)r * CH + col] = a[j];
            }
        }
    }
}

// ---------------- s_src / s_dst: one wave per node, shuffle reduce ----------------
template<int HEADS>
__global__ __launch_bounds__(256) void compute_s_w(
    const float* __restrict__ z, const float* __restrict__ a,
    float* __restrict__ s_src, float* __restrict__ s_dst)
{
    const int wid = threadIdx.x >> 6;
    const int lane = threadIdx.x & 63;
    const int n = blockIdx.x * 4 + wid;
    if (n >= NN) return;
    const int D = CH / HEADS;
    const float2 v = *(const float2*)&z[(size_t)n * CH + lane * 2];
    const int c0 = lane * 2;
    const int head = c0 / D;
    const int d0 = c0 % D;
    float ps = v.x * a[head * 2 * D + d0]     + v.y * a[head * 2 * D + d0 + 1];
    float pd = v.x * a[head * 2 * D + D + d0] + v.y * a[head * 2 * D + D + d0 + 1];
    #pragma unroll
    for (int off = 1; off < D / 2; off <<= 1) {
        ps += __shfl_xor(ps, off, 64);
        pd += __shfl_xor(pd, off, 64);
    }
    if ((lane % (D / 2)) == 0) {
        s_src[n * HEADS + head] = ps;
        s_dst[n * HEADS + head] = pd;
    }
}

// ---------------- CSR build ----------------
__global__ __launch_bounds__(256) void zero_cc(int* __restrict__ counts, int* __restrict__ cursor)
{
    int i = blockIdx.x * 256 + threadIdx.x;
    if (i < NN) { counts[i] = 0; cursor[i] = 0; }
}

__global__ void count_k(const int* __restrict__ dst, int* __restrict__ counts)
{
    int e = blockIdx.x * blockDim.x + threadIdx.x;
    if (e < NE) atomicAdd(&counts[dst[e]], 1);
}

__global__ __launch_bounds__(256) void scan1(const int* __restrict__ counts,
                                             int* __restrict__ exc, int* __restrict__ bsum)
{
    __shared__ int s[256];
    const int t = threadIdx.x;
    const int i = blockIdx.x * 256 + t;
    const int val = (i < NN) ? counts[i] : 0;
    s[t] = val;
    __syncthreads();
    #pragma unroll
    for (int off = 1; off < 256; off <<= 1) {
        int v = (t >= off) ? s[t - off] : 0;
        __syncthreads();
        s[t] += v;
        __syncthreads();
    }
    if (i < NN) exc[i] = s[t] - val;
    if (t == 255) bsum[blockIdx.x] = s[255];
}

__global__ __launch_bounds__(256) void scan2(const int* __restrict__ bsum,
                                             int* __restrict__ bexc)
{
    __shared__ int s[256];
    const int t = threadIdx.x;
    const int val = (t < NBLK) ? bsum[t] : 0;
    s[t] = val;
    __syncthreads();
    #pragma unroll
    for (int off = 1; off < 256; off <<= 1) {
        int v = (t >= off) ? s[t - off] : 0;
        __syncthreads();
        s[t] += v;
        __syncthreads();
    }
    bexc[t] = s[t] - val;
}

__global__ __launch_bounds__(256) void scan3(const int* __restrict__ exc,
                                             const int* __restrict__ bexc,
                                             int* __restrict__ offsets)
{
    const int i = blockIdx.x * 256 + threadIdx.x;
    if (i < NN) offsets[i] = exc[i] + bexc[i >> 8];
    if (i == 0) offsets[NN] = NE;
}

// scatter permuted SOURCE ids directly: es[p] = src[e]
__global__ void scatter_es(const int* __restrict__ src, const int* __restrict__ dst,
                           const int* __restrict__ offsets, int* __restrict__ cursor,
                           int* __restrict__ es)
{
    int e = blockIdx.x * blockDim.x + threadIdx.x;
    if (e >= NE) return;
    int d = dst[e];
    int p = offsets[d] + atomicAdd(&cursor[d], 1);
    es[p] = src[e];
}

// ---------------- fused softmax + aggregation: one WAVE per dst node ----------------
template<int H, bool ELU>
__global__ __launch_bounds__(256) void fused_agg(
    const int* __restrict__ offsets, const int* __restrict__ es,
    const float* __restrict__ s_src, const float* __restrict__ s_dst,
    const float* __restrict__ z, float* __restrict__ out)
{
    const int wid = threadIdx.x >> 6;
    const int lane = threadIdx.x & 63;
    const int n = blockIdx.x * 4 + wid;     // NN % 4 == 0, exact
    const int beg = offsets[n], end = offsets[n + 1];
    const int deg = end - beg;

    __shared__ float alpha_sh[4][128][H];
    __shared__ int   es_sh[4][128];
    __shared__ int   maxdeg;
    if (threadIdx.x == 0) maxdeg = 0;
    __syncthreads();
    if (lane == 0) atomicMax(&maxdeg, deg);
    __syncthreads();
    const int nch = (maxdeg + 127) >> 7;    // uniform across block -> safe barriers

    float sdv[H];
    #pragma unroll
    for (int h = 0; h < H; ++h) sdv[h] = s_dst[(size_t)n * H + h];

    // ---- pass 1: per-head max ----
    float m[H];
    #pragma unroll
    for (int h = 0; h < H; ++h) m[h] = -INFINITY;
    for (int i = beg + lane; i < end; i += 64) {
        const int s = es[i];
        if (H == 4) {
            const float4 sv = *(const float4*)&s_src[(size_t)s * 4];
            const float svv[4] = {sv.x, sv.y, sv.z, sv.w};
            #pragma unroll
            for (int h = 0; h < 4; ++h) {
                float v = svv[h] + sdv[h];
                v = v > 0.f ? v : 0.01f * v;
                m[h] = fmaxf(m[h], v);
            }
        } else {
            float v = s_src[s] + sdv[0];
            v = v > 0.f ? v : 0.01f * v;
            m[0] = fmaxf(m[0], v);
        }
    }
    #pragma unroll
    for (int h = 0; h < H; ++h)
        #pragma unroll
        for (int off = 1; off < 64; off <<= 1)
            m[h] = fmaxf(m[h], __shfl_xor(m[h], off, 64));

    // ---- pass 2: per-head sum of exp ----
    float ssum[H];
    #pragma unroll
    for (int h = 0; h < H; ++h) ssum[h] = 0.f;
    for (int i = beg + lane; i < end; i += 64) {
        const int s = es[i];
        if (H == 4) {
            const float4 sv = *(const float4*)&s_src[(size_t)s * 4];
            const float svv[4] = {sv.x, sv.y, sv.z, sv.w};
            #pragma unroll
            for (int h = 0; h < 4; ++h) {
                float v = svv[h] + sdv[h];
                v = v > 0.f ? v : 0.01f * v;
                ssum[h] += __expf(v - m[h]);
            }
        } else {
            float v = s_src[s] + sdv[0];
            v = v > 0.f ? v : 0.01f * v;
            ssum[0] += __expf(v - m[0]);
        }
    }
    #pragma unroll
    for (int h = 0; h < H; ++h) {
        #pragma unroll
        for (int off = 1; off < 64; off <<= 1)
            ssum[h] += __shfl_xor(ssum[h], off, 64);
    }
    float inv[H];
    #pragma unroll
    for (int h = 0; h < H; ++h) inv[h] = 1.0f / fmaxf(ssum[h], 1e-9f);

    // ---- pass 3: chunked alpha + accumulate ----
    const int myh = (H == 4) ? (lane >> 4) : 0;
    float2 acc = make_float2(0.f, 0.f);
    for (int k = 0; k < nch; ++k) {
        const int base = beg + k * 128;
        int cnt = end - base;
        cnt = cnt < 0 ? 0 : (cnt > 128 ? 128 : cnt);
        for (int idx = lane; idx < cnt; idx += 64) {
            const int s = es[base + idx];
            es_sh[wid][idx] = s;
            if (H == 4) {
                const float4 sv = *(const float4*)&s_src[(size_t)s * 4];
                const float svv[4] = {sv.x, sv.y, sv.z, sv.w};
                float a4[4];
                #pragma unroll
                for (int h = 0; h < 4; ++h) {
                    float v = svv[h] + sdv[h];
                    v = v > 0.f ? v : 0.01f * v;
                    a4[h] = __expf(v - m[h]) * inv[h];
                }
                *(float4*)&alpha_sh[wid][idx][0] = make_float4(a4[0], a4[1], a4[2], a4[3]);
            } else {
                float v = s_src[s] + sdv[0];
                v = v > 0.f ? v : 0.01f * v;
                alpha_sh[wid][idx][0] = __expf(v - m[0]) * inv[0];
            }
        }
        __syncthreads();
        int j = 0;
        for (; j + 2 <= cnt; j += 2) {
            const int s0 = es_sh[wid][j],     s1 = es_sh[wid][j + 1];
            const float a0 = alpha_sh[wid][j][myh], a1 = alpha_sh[wid][j + 1][myh];
            const float2 z0 = *(const float2*)&z[(size_t)s0 * CH + lane * 2];
            const float2 z1 = *(const float2*)&z[(size_t)s1 * CH + lane * 2];
            acc.x = fmaf(a0, z0.x, acc.x); acc.y = fmaf(a0, z0.y, acc.y);
            acc.x = fmaf(a1, z1.x, acc.x); acc.y = fmaf(a1, z1.y, acc.y);
        }
        if (j < cnt) {
            const int s0 = es_sh[wid][j];
            const float a0 = alpha_sh[wid][j][myh];
            const float2 z0 = *(const float2*)&z[(size_t)s0 * CH + lane * 2];
            acc.x = fmaf(a0, z0.x, acc.x); acc.y = fmaf(a0, z0.y, acc.y);
        }
        __syncthreads();
    }

    if (ELU) {
        acc.x = acc.x > 0.f ? acc.x : expm1f(acc.x);
        acc.y = acc.y > 0.f ? acc.y : expm1f(acc.y);
    }
    *(float2*)&out[(size_t)n * CH + lane * 2] = acc;
}

// ---------------- host ----------------
extern "C" void kernel_launch(void* const* d_in, const int* in_sizes, int n_in,
                              void* d_out, int out_size, void* d_ws, size_t ws_size,
                              hipStream_t stream)
{
    const float* h   = (const float*)d_in[0];
    const float* W1  = (const float*)d_in[1];
    const float* a1  = (const float*)d_in[2];
    const float* W2  = (const float*)d_in[3];
    const float* a2  = (const float*)d_in[4];
    const int*   src = (const int*)d_in[5];
    const int*   dst = (const int*)d_in[6];
    float* out = (float*)d_out;

    char* ws = (char*)d_ws;
    unsigned short* Bthi1 = (unsigned short*)(ws + 0);        // 196608 B
    unsigned short* Btlo1 = (unsigned short*)(ws + 196608);   // 196608 B
    float* z       = (float*)(ws + 393216);                   // 25.6 MB
    float* h1      = (float*)(ws + 25993216);                 // 25.6 MB
    float* ss      = (float*)(ws + 51593216);                 // 800 KB
    float* sd      = (float*)(ws + 52393216);                 // 800 KB
    int*   counts  = (int*)  (ws + 53193216);                 // 200 KB
    int*   exc     = (int*)  (ws + 53393216);                 // 200 KB
    int*   bsum    = (int*)  (ws + 53593216);                 // 1 KB
    int*   bexc    = (int*)  (ws + 53594240);                 // 1 KB
    int*   offsets = (int*)  (ws + 53595264);                 // 200 KB (+4)
    int*   cursor  = (int*)  (ws + 53795344);                 // 200 KB
    int*   es      = (int*)  (ws + 53995344);                 // 3.2 MB
    unsigned short* Bthi2 = (unsigned short*)(ws + 57195344); // 32 KB
    unsigned short* Btlo2 = (unsigned short*)(ws + 57228112); // 32 KB

    const int EB = 256;
    const int egrid = (NE + EB - 1) / EB;
    const int ggrid = (NN + GBM - 1) / GBM;
    const int sgrid = (NN + 3) / 4;
    const int agrid = NN / 4;

    // --- CSR build (shared by both layers) ---
    zero_cc<<<NBLK, 256, 0, stream>>>(counts, cursor);
    count_k<<<egrid, EB, 0, stream>>>(dst, counts);
    scan1<<<NBLK, 256, 0, stream>>>(counts, exc, bsum);
    scan2<<<1, 256, 0, stream>>>(bsum, bexc);
    scan3<<<NBLK, 256, 0, stream>>>(exc, bexc, offsets);
    scatter_es<<<egrid, EB, 0, stream>>>(src, dst, offsets, cursor, es);

    // --- weight prep (split bf16, tiled+swizzled) ---
    prep_b1<<<(CH * IND + 255) / 256, 256, 0, stream>>>(W1, Bthi1, Btlo1);
    prep_b2<<<(CH * CH + 255) / 256, 256, 0, stream>>>(W2, Bthi2, Btlo2);

    // --- layer 1 ---
    gemm_split<<<ggrid, 256, 0, stream>>>(h, Bthi1, Btlo1, z, NN, IND);
    compute_s_w<4><<<sgrid, 256, 0, stream>>>(z, a1, ss, sd);
    fused_agg<4, true><<<agrid, 256, 0, stream>>>(offsets, es, ss, sd, z, h1);

    // --- layer 2 ---
    gemm_split<<<ggrid, 256, 0, stream>>>(h1, Bthi2, Btlo2, z, NN, CH);
    compute_s_w<1><<<sgrid, 256, 0, stream>>>(z, a2, ss, sd);
    fused_agg<1, false><<<agrid, 256, 0, stream>>>(offsets, es, ss, sd, z, out);
}

// Round 8
// 311.310 us; speedup vs baseline: 1.0166x; 1.0166x over previous
//
#include <hip/hip_runtime.h>

#define NN 50000
#define NE 800000
#define IND 768
#define CH  128   // output channels per node for both layers
#define NBLK 196  // ceil(NN/256)

typedef __attribute__((ext_vector_type(8))) short bf16x8;
typedef __attribute__((ext_vector_type(4))) float f32x4;

// ---------------- bf16 split helpers ----------------
__device__ __forceinline__ unsigned short bf16_rne(float f) {
    unsigned u = __float_as_uint(f);
    u += 0x7fffu + ((u >> 16) & 1u);
    return (unsigned short)(u >> 16);
}
__device__ __forceinline__ float bf16_to_f(unsigned short b) {
    return __uint_as_float(((unsigned)b) << 16);
}

// ---------------- prep: W -> K-tiled, 8-way-swizzled bf16 hi/lo planes ----------------
// Per plane: [K/32 tiles][4096 ushorts]. Granule j of row n stored at
// g = n*4 + (j ^ ((n>>1)&3)); verified 0 bank conflicts (round 7 PMC).
__global__ void prep_b1(const float* __restrict__ W1,
                        unsigned short* __restrict__ Bhi, unsigned short* __restrict__ Blo)
{
    int idx = blockIdx.x * blockDim.x + threadIdx.x;   // n*IND + k
    if (idx >= CH * IND) return;
    int n = idx / IND, k = idx % IND;
    float v = W1[(size_t)(n >> 5) * IND * 32 + (size_t)k * 32 + (n & 31)];
    int kt = k >> 5, kk = k & 31, j = kk >> 3, e = kk & 7;
    int g = n * 4 + (j ^ ((n >> 1) & 3));
    int off = kt * 4096 + g * 8 + e;
    unsigned short hi = bf16_rne(v);
    float lo = v - bf16_to_f(hi);
    Bhi[off] = hi;
    Blo[off] = bf16_rne(lo);
}

__global__ void prep_b2(const float* __restrict__ W2,
                        unsigned short* __restrict__ Bhi, unsigned short* __restrict__ Blo)
{
    int idx = blockIdx.x * blockDim.x + threadIdx.x;   // n*CH + k
    if (idx >= CH * CH) return;
    int n = idx / CH, k = idx % CH;
    float v = W2[(size_t)k * CH + n];
    int kt = k >> 5, kk = k & 31, j = kk >> 3, e = kk & 7;
    int g = n * 4 + (j ^ ((n >> 1) & 3));
    int off = kt * 4096 + g * 8 + e;
    unsigned short hi = bf16_rne(v);
    float lo = v - bf16_to_f(hi);
    Bhi[off] = hi;
    Blo[off] = bf16_rne(lo);
}

// ---------------- GEMM: wave tile 16x128, A global->reg 2-deep, B LDS dbuf ----------------
#define GBM 64
#define GBK 32

__device__ __forceinline__ void gemm_body(
    int kt, int nt, bool wvalid, const float* aptr,
    float4& c0, float4& c1,                         // A set: consumed (tile kt), refilled (tile kt+2)
    const unsigned short (*BsCur)[4096],            // LDS buf holding tile kt
    unsigned short (*BsNxt)[4096],                  // LDS buf for tile kt+1 DMA
    const unsigned short* __restrict__ Bthi, const unsigned short* __restrict__ Btlo,
    int w, int lane, const int* boff, f32x4* acc)
{
    // ---- convert A (tile kt) from regs ----
    float f[8] = {c0.x, c0.y, c0.z, c0.w, c1.x, c1.y, c1.z, c1.w};
    unsigned short hi[8], lo[8];
    #pragma unroll
    for (int q = 0; q < 8; ++q) {
        hi[q] = bf16_rne(f[q]);
        lo[q] = bf16_rne(f[q] - bf16_to_f(hi[q]));
    }
    const bf16x8 ahi = *(const bf16x8*)hi;
    const bf16x8 alo = *(const bf16x8*)lo;

    // ---- refill this set with tile kt+2 (consumed two barriers from now) ----
    if (kt + 2 < nt && wvalid) {
        const float* p = aptr + (size_t)(kt + 2) * GBK;
        c0 = *(const float4*)p;
        c1 = *(const float4*)(p + 4);
    }
    // ---- DMA B tile kt+1 into the other buffer ----
    if (kt + 1 < nt) {
        #pragma unroll
        for (int i = 0; i < 4; ++i) {
            const int c = w * 4 + i;               // 0..15
            const int plane = c >> 3;
            const int co = (c & 7) * 512;          // ushort offset in tile
            const unsigned short* gs =
                (plane ? Btlo : Bthi) + (size_t)(kt + 1) * 4096 + co + lane * 8;
            __builtin_amdgcn_global_load_lds(
                (const __attribute__((address_space(1))) unsigned int*)gs,
                (__attribute__((address_space(3))) unsigned int*)&BsNxt[plane][co],
                16, 0, 0);
        }
    }
    // ---- 8 ni x 3 MFMA over current B buffer ----
    #pragma unroll
    for (int ni = 0; ni < 8; ++ni) {
        const bf16x8 bhi = *(const bf16x8*)&BsCur[0][boff[ni]];
        const bf16x8 blo = *(const bf16x8*)&BsCur[1][boff[ni]];
        acc[ni] = __builtin_amdgcn_mfma_f32_16x16x32_bf16(ahi, bhi, acc[ni], 0, 0, 0);
        acc[ni] = __builtin_amdgcn_mfma_f32_16x16x32_bf16(ahi, blo, acc[ni], 0, 0, 0);
        acc[ni] = __builtin_amdgcn_mfma_f32_16x16x32_bf16(alo, bhi, acc[ni], 0, 0, 0);
    }
    __syncthreads();   // all waves done with BsCur; BsNxt DMA drained
}

__global__ __launch_bounds__(256) void gemm_split(
    const float* __restrict__ A,
    const unsigned short* __restrict__ Bthi, const unsigned short* __restrict__ Btlo,
    float* __restrict__ C, int M, int K)
{
    __shared__ unsigned short Bs[2][2][4096];   // [buf][plane][128 rows x 4 granules x 8]

    const int t = threadIdx.x;
    const int lane = t & 63;
    const int w = t >> 6;                 // wave -> rows m0+w*16 .. +15 (full 128 cols)
    const int lrow = lane & 15, kg = lane >> 4;
    const int m0 = blockIdx.x * GBM;

    const bool wvalid = (m0 + w * 16) < M;        // M%16==0 -> wave-uniform
    const int arow = m0 + w * 16 + lrow;
    const float* aptr = A + (size_t)(wvalid ? arow : 0) * K + kg * 8;

    int boff[8];
    #pragma unroll
    for (int ni = 0; ni < 8; ++ni) {
        const int n = ni * 16 + lrow;
        boff[ni] = (n * 4 + (kg ^ ((n >> 1) & 3))) * 8;
    }

    f32x4 acc[8];
    #pragma unroll
    for (int i = 0; i < 8; ++i) acc[i] = (f32x4)(0.f);

    const int nt = K / GBK;               // 24 or 4 (always even)

    // ---- prologue: A sets <- tiles 0,1; DMA B tile 0 -> buf0 ----
    float4 a00 = make_float4(0.f,0.f,0.f,0.f), a10 = a00, a01 = a00, a11 = a00;
    if (wvalid) {
        a00 = *(const float4*)aptr;
        a10 = *(const float4*)(aptr + 4);
        a01 = *(const float4*)(aptr + GBK);
        a11 = *(const float4*)(aptr + GBK + 4);
    }
    #pragma unroll
    for (int i = 0; i < 4; ++i) {
        const int c = w * 4 + i;
        const int plane = c >> 3;
        const int co = (c & 7) * 512;
        const unsigned short* gs = (plane ? Btlo : Bthi) + co + lane * 8;
        __builtin_amdgcn_global_load_lds(
            (const __attribute__((address_space(1))) unsigned int*)gs,
            (__attribute__((address_space(3))) unsigned int*)&Bs[0][plane][co],
            16, 0, 0);
    }
    __syncthreads();

    // ---- main loop, 2-unrolled so set/buffer indices are compile-time ----
    for (int kt2 = 0; kt2 < nt; kt2 += 2) {
        gemm_body(kt2,     nt, wvalid, aptr, a00, a10, Bs[0], Bs[1], Bthi, Btlo, w, lane, boff, acc);
        gemm_body(kt2 + 1, nt, wvalid, aptr, a01, a11, Bs[1], Bs[0], Bthi, Btlo, w, lane, boff, acc);
    }

    // ---- C write: col = lane&15 (+16*ni), row = kg*4 + j ----
    if (wvalid) {
        #pragma unroll
        for (int ni = 0; ni < 8; ++ni) {
            const int col = ni * 16 + lrow;
            const f32x4 a = acc[ni];
            #pragma unroll
            for (int j = 0; j < 4; ++j) {
                const int r = m0 + w * 16 + kg * 4 + j;
                C[(size_t)r * CH + col] = a[j];
            }
        }
    }
}

// ---------------- s_src / s_dst: one wave per node, shuffle reduce ----------------
template<int HEADS>
__global__ __launch_bounds__(256) void compute_s_w(
    const float* __restrict__ z, const float* __restrict__ a,
    float* __restrict__ s_src, float* __restrict__ s_dst)
{
    const int wid = threadIdx.x >> 6;
    const int lane = threadIdx.x & 63;
    const int n = blockIdx.x * 4 + wid;
    if (n >= NN) return;
    const int D = CH / HEADS;
    const float2 v = *(const float2*)&z[(size_t)n * CH + lane * 2];
    const int c0 = lane * 2;
    const int head = c0 / D;
    const int d0 = c0 % D;
    float ps = v.x * a[head * 2 * D + d0]     + v.y * a[head * 2 * D + d0 + 1];
    float pd = v.x * a[head * 2 * D + D + d0] + v.y * a[head * 2 * D + D + d0 + 1];
    #pragma unroll
    for (int off = 1; off < D / 2; off <<= 1) {
        ps += __shfl_xor(ps, off, 64);
        pd += __shfl_xor(pd, off, 64);
    }
    if ((lane % (D / 2)) == 0) {
        s_src[n * HEADS + head] = ps;
        s_dst[n * HEADS + head] = pd;
    }
}

// ---------------- CSR build ----------------
__global__ __launch_bounds__(256) void zero_cc(int* __restrict__ counts, int* __restrict__ cursor)
{
    int i = blockIdx.x * 256 + threadIdx.x;
    if (i < NN) { counts[i] = 0; cursor[i] = 0; }
}

__global__ void count_k(const int* __restrict__ dst, int* __restrict__ counts)
{
    int e = blockIdx.x * blockDim.x + threadIdx.x;
    if (e < NE) atomicAdd(&counts[dst[e]], 1);
}

__global__ __launch_bounds__(256) void scan1(const int* __restrict__ counts,
                                             int* __restrict__ exc, int* __restrict__ bsum)
{
    __shared__ int s[256];
    const int t = threadIdx.x;
    const int i = blockIdx.x * 256 + t;
    const int val = (i < NN) ? counts[i] : 0;
    s[t] = val;
    __syncthreads();
    #pragma unroll
    for (int off = 1; off < 256; off <<= 1) {
        int v = (t >= off) ? s[t - off] : 0;
        __syncthreads();
        s[t] += v;
        __syncthreads();
    }
    if (i < NN) exc[i] = s[t] - val;
    if (t == 255) bsum[blockIdx.x] = s[255];
}

__global__ __launch_bounds__(256) void scan2(const int* __restrict__ bsum,
                                             int* __restrict__ bexc)
{
    __shared__ int s[256];
    const int t = threadIdx.x;
    const int val = (t < NBLK) ? bsum[t] : 0;
    s[t] = val;
    __syncthreads();
    #pragma unroll
    for (int off = 1; off < 256; off <<= 1) {
        int v = (t >= off) ? s[t - off] : 0;
        __syncthreads();
        s[t] += v;
        __syncthreads();
    }
    bexc[t] = s[t] - val;
}

__global__ __launch_bounds__(256) void scan3(const int* __restrict__ exc,
                                             const int* __restrict__ bexc,
                                             int* __restrict__ offsets)
{
    const int i = blockIdx.x * 256 + threadIdx.x;
    if (i < NN) offsets[i] = exc[i] + bexc[i >> 8];
    if (i == 0) offsets[NN] = NE;
}

// scatter permuted SOURCE ids directly: es[p] = src[e]
__global__ void scatter_es(const int* __restrict__ src, const int* __restrict__ dst,
                           const int* __restrict__ offsets, int* __restrict__ cursor,
                           int* __restrict__ es)
{
    int e = blockIdx.x * blockDim.x + threadIdx.x;
    if (e >= NE) return;
    int d = dst[e];
    int p = offsets[d] + atomicAdd(&cursor[d], 1);
    es[p] = src[e];
}

// ---------------- fused softmax + aggregation: one WAVE per dst node ----------------
template<int H, bool ELU>
__global__ __launch_bounds__(256) void fused_agg(
    const int* __restrict__ offsets, const int* __restrict__ es,
    const float* __restrict__ s_src, const float* __restrict__ s_dst,
    const float* __restrict__ z, float* __restrict__ out)
{
    const int wid = threadIdx.x >> 6;
    const int lane = threadIdx.x & 63;
    const int n = blockIdx.x * 4 + wid;     // NN % 4 == 0, exact
    const int beg = offsets[n], end = offsets[n + 1];
    const int deg = end - beg;

    __shared__ float alpha_sh[4][128][H];
    __shared__ int   es_sh[4][128];
    __shared__ int   maxdeg;
    if (threadIdx.x == 0) maxdeg = 0;
    __syncthreads();
    if (lane == 0) atomicMax(&maxdeg, deg);
    __syncthreads();
    const int nch = (maxdeg + 127) >> 7;    // uniform across block -> safe barriers

    float sdv[H];
    #pragma unroll
    for (int h = 0; h < H; ++h) sdv[h] = s_dst[(size_t)n * H + h];

    // ---- pass 1: per-head max ----
    float m[H];
    #pragma unroll
    for (int h = 0; h < H; ++h) m[h] = -INFINITY;
    for (int i = beg + lane; i < end; i += 64) {
        const int s = es[i];
        if (H == 4) {
            const float4 sv = *(const float4*)&s_src[(size_t)s * 4];
            const float svv[4] = {sv.x, sv.y, sv.z, sv.w};
            #pragma unroll
            for (int h = 0; h < 4; ++h) {
                float v = svv[h] + sdv[h];
                v = v > 0.f ? v : 0.01f * v;
                m[h] = fmaxf(m[h], v);
            }
        } else {
            float v = s_src[s] + sdv[0];
            v = v > 0.f ? v : 0.01f * v;
            m[0] = fmaxf(m[0], v);
        }
    }
    #pragma unroll
    for (int h = 0; h < H; ++h)
        #pragma unroll
        for (int off = 1; off < 64; off <<= 1)
            m[h] = fmaxf(m[h], __shfl_xor(m[h], off, 64));

    // ---- pass 2: per-head sum of exp ----
    float ssum[H];
    #pragma unroll
    for (int h = 0; h < H; ++h) ssum[h] = 0.f;
    for (int i = beg + lane; i < end; i += 64) {
        const int s = es[i];
        if (H == 4) {
            const float4 sv = *(const float4*)&s_src[(size_t)s * 4];
            const float svv[4] = {sv.x, sv.y, sv.z, sv.w};
            #pragma unroll
            for (int h = 0; h < 4; ++h) {
                float v = svv[h] + sdv[h];
                v = v > 0.f ? v : 0.01f * v;
                ssum[h] += __expf(v - m[h]);
            }
        } else {
            float v = s_src[s] + sdv[0];
            v = v > 0.f ? v : 0.01f * v;
            ssum[0] += __expf(v - m[0]);
        }
    }
    #pragma unroll
    for (int h = 0; h < H; ++h) {
        #pragma unroll
        for (int off = 1; off < 64; off <<= 1)
            ssum[h] += __shfl_xor(ssum[h], off, 64);
    }
    float inv[H];
    #pragma unroll
    for (int h = 0; h < H; ++h) inv[h] = 1.0f / fmaxf(ssum[h], 1e-9f);

    // ---- pass 3: chunked alpha + accumulate ----
    const int myh = (H == 4) ? (lane >> 4) : 0;
    float2 acc = make_float2(0.f, 0.f);
    for (int k = 0; k < nch; ++k) {
        const int base = beg + k * 128;
        int cnt = end - base;
        cnt = cnt < 0 ? 0 : (cnt > 128 ? 128 : cnt);
        for (int idx = lane; idx < cnt; idx += 64) {
            const int s = es[base + idx];
            es_sh[wid][idx] = s;
            if (H == 4) {
                const float4 sv = *(const float4*)&s_src[(size_t)s * 4];
                const float svv[4] = {sv.x, sv.y, sv.z, sv.w};
                float a4[4];
                #pragma unroll
                for (int h = 0; h < 4; ++h) {
                    float v = svv[h] + sdv[h];
                    v = v > 0.f ? v : 0.01f * v;
                    a4[h] = __expf(v - m[h]) * inv[h];
                }
                *(float4*)&alpha_sh[wid][idx][0] = make_float4(a4[0], a4[1], a4[2], a4[3]);
            } else {
                float v = s_src[s] + sdv[0];
                v = v > 0.f ? v : 0.01f * v;
                alpha_sh[wid][idx][0] = __expf(v - m[0]) * inv[0];
            }
        }
        __syncthreads();
        int j = 0;
        for (; j + 2 <= cnt; j += 2) {
            const int s0 = es_sh[wid][j],     s1 = es_sh[wid][j + 1];
            const float a0 = alpha_sh[wid][j][myh], a1 = alpha_sh[wid][j + 1][myh];
            const float2 z0 = *(const float2*)&z[(size_t)s0 * CH + lane * 2];
            const float2 z1 = *(const float2*)&z[(size_t)s1 * CH + lane * 2];
            acc.x = fmaf(a0, z0.x, acc.x); acc.y = fmaf(a0, z0.y, acc.y);
            acc.x = fmaf(a1, z1.x, acc.x); acc.y = fmaf(a1, z1.y, acc.y);
        }
        if (j < cnt) {
            const int s0 = es_sh[wid][j];
            const float a0 = alpha_sh[wid][j][myh];
            const float2 z0 = *(const float2*)&z[(size_t)s0 * CH + lane * 2];
            acc.x = fmaf(a0, z0.x, acc.x); acc.y = fmaf(a0, z0.y, acc.y);
        }
        __syncthreads();
    }

    if (ELU) {
        acc.x = acc.x > 0.f ? acc.x : expm1f(acc.x);
        acc.y = acc.y > 0.f ? acc.y : expm1f(acc.y);
    }
    *(float2*)&out[(size_t)n * CH + lane * 2] = acc;
}

// ---------------- host ----------------
extern "C" void kernel_launch(void* const* d_in, const int* in_sizes, int n_in,
                              void* d_out, int out_size, void* d_ws, size_t ws_size,
                              hipStream_t stream)
{
    const float* h   = (const float*)d_in[0];
    const float* W1  = (const float*)d_in[1];
    const float* a1  = (const float*)d_in[2];
    const float* W2  = (const float*)d_in[3];
    const float* a2  = (const float*)d_in[4];
    const int*   src = (const int*)d_in[5];
    const int*   dst = (const int*)d_in[6];
    float* out = (float*)d_out;

    char* ws = (char*)d_ws;
    unsigned short* Bthi1 = (unsigned short*)(ws + 0);        // 196608 B
    unsigned short* Btlo1 = (unsigned short*)(ws + 196608);   // 196608 B
    float* z       = (float*)(ws + 393216);                   // 25.6 MB
    float* h1      = (float*)(ws + 25993216);                 // 25.6 MB
    float* ss      = (float*)(ws + 51593216);                 // 800 KB
    float* sd      = (float*)(ws + 52393216);                 // 800 KB
    int*   counts  = (int*)  (ws + 53193216);                 // 200 KB
    int*   exc     = (int*)  (ws + 53393216);                 // 200 KB
    int*   bsum    = (int*)  (ws + 53593216);                 // 1 KB
    int*   bexc    = (int*)  (ws + 53594240);                 // 1 KB
    int*   offsets = (int*)  (ws + 53595264);                 // 200 KB (+4)
    int*   cursor  = (int*)  (ws + 53795344);                 // 200 KB
    int*   es      = (int*)  (ws + 53995344);                 // 3.2 MB
    unsigned short* Bthi2 = (unsigned short*)(ws + 57195344); // 32 KB
    unsigned short* Btlo2 = (unsigned short*)(ws + 57228112); // 32 KB

    const int EB = 256;
    const int egrid = (NE + EB - 1) / EB;
    const int ggrid = (NN + GBM - 1) / GBM;
    const int sgrid = (NN + 3) / 4;
    const int agrid = NN / 4;

    // --- CSR build (shared by both layers) ---
    zero_cc<<<NBLK, 256, 0, stream>>>(counts, cursor);
    count_k<<<egrid, EB, 0, stream>>>(dst, counts);
    scan1<<<NBLK, 256, 0, stream>>>(counts, exc, bsum);
    scan2<<<1, 256, 0, stream>>>(bsum, bexc);
    scan3<<<NBLK, 256, 0, stream>>>(exc, bexc, offsets);
    scatter_es<<<egrid, EB, 0, stream>>>(src, dst, offsets, cursor, es);

    // --- weight prep (split bf16, tiled+swizzled) ---
    prep_b1<<<(CH * IND + 255) / 256, 256, 0, stream>>>(W1, Bthi1, Btlo1);
    prep_b2<<<(CH * CH + 255) / 256, 256, 0, stream>>>(W2, Bthi2, Btlo2);

    // --- layer 1 ---
    gemm_split<<<ggrid, 256, 0, stream>>>(h, Bthi1, Btlo1, z, NN, IND);
    compute_s_w<4><<<sgrid, 256, 0, stream>>>(z, a1, ss, sd);
    fused_agg<4, true><<<agrid, 256, 0, stream>>>(offsets, es, ss, sd, z, h1);

    // --- layer 2 ---
    gemm_split<<<ggrid, 256, 0, stream>>>(h1, Bthi2, Btlo2, z, NN, CH);
    compute_s_w<1><<<sgrid, 256, 0, stream>>>(z, a2, ss, sd);
    fused_agg<1, false><<<agrid, 256, 0, stream>>>(offsets, es, ss, sd, z, out);
}